// Round 11
// baseline (2980.965 us; speedup 1.0000x reference)
//
#include <hip/hip_runtime.h>

#define T_ 1024
#define I_ 18
#define GUARD (1 << 18)

typedef _Float16 f16;
typedef _Float16 f16x8 __attribute__((ext_vector_type(8)));
typedef _Float16 f16x4 __attribute__((ext_vector_type(4)));
typedef float f32x4 __attribute__((ext_vector_type(4)));

#define MFMA16(a, b, c) __builtin_amdgcn_mfma_f32_16x16x32_f16((a), (b), (c), 0, 0, 0)
#define SB() __builtin_amdgcn_sched_barrier(0)

// ---- ws: hb0[4][64][4096] f16 | gb1[4][64][12288] f16 | flags | ids | dec
#define HB0_ELEMS (4 * 64 * 4096)
#define GB1_ELEMS (4 * 64 * 12288)
#define NFLAGS (64 * 64)  // [chunk][grp8][wave8]; grp 0=fh0 1=fgiE 2=fgiO 3=fg1pE 4=fg1pO 5=fh1p
// LDS 160KB exactly: weights kt5..7 [144*512] f16 | hring [2*4096] f16
#define LDS_BYTES 163840

struct TrueT { static constexpr bool value = true; };
struct FalseT { static constexpr bool value = false; };

__global__ void init_ws(int* __restrict__ flg) {
  int i = blockIdx.x * blockDim.x + threadIdx.x;
  if (i < NFLAGS + 256 + 1) flg[i] = 0;
}

__device__ __forceinline__ float sigm(float v) {
  return __builtin_amdgcn_rcpf(1.f + __expf(-v));
}
__device__ __forceinline__ float tanh_fast(float v) {
  v = fmaxf(v, -15.f);
  float e = __expf(-2.f * v);
  return (1.f - e) * __builtin_amdgcn_rcpf(1.f + e);
}
__device__ __forceinline__ f16x8 cvt8(const float* q) {
  const f32x4* a = (const f32x4*)q;
  f32x4 u = a[0], v = a[1];
  f16x8 r;
  r[0] = (f16)u[0]; r[1] = (f16)u[1]; r[2] = (f16)u[2]; r[3] = (f16)u[3];
  r[4] = (f16)v[0]; r[5] = (f16)v[1]; r[6] = (f16)v[2]; r[7] = (f16)v[3];
  return r;
}

template <bool FAST>
__device__ __forceinline__ f16x8 ldh(const f16* p) {
  f16x8 r;
  if (FAST) asm volatile("global_load_dwordx4 %0, %1, off nt" : "=&v"(r) : "v"(p));
  else asm volatile("global_load_dwordx4 %0, %1, off sc0 sc1" : "=&v"(r) : "v"(p));
  return r;
}
template <bool FAST>
__device__ __forceinline__ f16x4 ldg8(const f16* p) {
  f16x4 r;
  if (FAST) asm volatile("global_load_dwordx2 %0, %1, off nt" : "=&v"(r) : "v"(p));
  else asm volatile("global_load_dwordx2 %0, %1, off sc0 sc1" : "=&v"(r) : "v"(p));
  return r;
}
template <bool FAST>
__device__ __forceinline__ void stg16(f16* p, f16x8 v) {
  if (FAST) asm volatile("global_store_dwordx4 %0, %1, off" ::"v"(p), "v"(v) : "memory");
  else asm volatile("global_store_dwordx4 %0, %1, off sc0 sc1" ::"v"(p), "v"(v) : "memory");
}
template <bool FAST>
__device__ __forceinline__ void stg8(f16* p, f16x4 v) {
  if (FAST) asm volatile("global_store_dwordx2 %0, %1, off" ::"v"(p), "v"(v) : "memory");
  else asm volatile("global_store_dwordx2 %0, %1, off sc0 sc1" ::"v"(p), "v"(v) : "memory");
}
template <bool FAST>
__device__ __forceinline__ void stf(int* p, int v) {
  if (FAST) asm volatile("global_store_dword %0, %1, off" ::"v"(p), "v"(v) : "memory");
  else asm volatile("global_store_dword %0, %1, off sc0 sc1" ::"v"(p), "v"(v) : "memory");
}
template <bool FAST>
__device__ __forceinline__ int ldf(const int* p) {  // flag load + full drain
  int r;
  if (FAST)
    asm volatile("global_load_dword %0, %1, off nt\n\ts_waitcnt vmcnt(0)"
                 : "=&v"(r) : "v"(p) : "memory");
  else
    asm volatile("global_load_dword %0, %1, off sc0 sc1\n\ts_waitcnt vmcnt(0)"
                 : "=&v"(r) : "v"(p) : "memory");
  return r;
}
__device__ __forceinline__ int ld_sys(const int* p) {
  int r;
  asm volatile("global_load_dword %0, %1, off sc0 sc1\n\ts_waitcnt vmcnt(0)"
               : "=&v"(r) : "v"(p) : "memory");
  return r;
}
__device__ __forceinline__ void st_sys(int* p, int v) { stf<false>(p, v); }
__device__ __forceinline__ f32x4 ldx4(const float* p) {
  f32x4 r;
  asm volatile("global_load_dwordx4 %0, %1, off" : "=&v"(r) : "v"(p));
  return r;
}

// 256 blocks x 512 threads, 1 block/CU (160KB LDS).
//  bx 0..63   : L0  (h0 recurrence, intra-CU LDS ring),       c = bx
//  bx 64..191 : GI1 (gi1 = W_ih1 h0 + b_ih1), c=(bx-64)&63, parity=(bx-64)>>6
//  bx 192..255: HH1 (h1 recurrence + head),                   c = bx-192
// All 4 blocks of chunk c are == c (mod 8) -> same XCD under round-robin.
// waves_per_eu(2,2): pin allocator occupancy to 2 waves/SIMD -> 256-VGPR budget
// (launch_bounds(512,2) alone left the heuristic at 4 waves -> 128 cap -> spill).
__global__ void __launch_bounds__(512)
__attribute__((amdgpu_waves_per_eu(2, 2))) gru_main(
    const float* __restrict__ x, const float* __restrict__ Wih0,
    const float* __restrict__ Whh0, const float* __restrict__ Wih1,
    const float* __restrict__ Whh1, const float* __restrict__ bih0,
    const float* __restrict__ bhh0, const float* __restrict__ bih1,
    const float* __restrict__ bhh1, const float* __restrict__ fcw,
    const float* __restrict__ fcb, f16* __restrict__ hb0,
    f16* __restrict__ gb1, int* __restrict__ flags, int* __restrict__ ids,
    int* __restrict__ dec, float* __restrict__ out) {
  extern __shared__ f16 lds[];       // [144*512] W kt5..7 | [2*4096] hring
  f16* hring = lds + 144 * 512;

  const int tid = threadIdx.x;
  const int wv = tid >> 6, lane = tid & 63;
  const int lrow = lane & 15, lgrp = lane >> 4;
  const int bx = blockIdx.x;
  const int stage = (bx < 64) ? 0 : (bx < 192) ? 1 : 2;
  const int c = (stage == 0) ? bx : (stage == 1) ? ((bx - 64) & 63) : (bx - 192);
  const int par = (stage == 1) ? ((bx - 64) >> 6) : 0;

  const float* Wm = (stage == 0) ? Whh0 : (stage == 1) ? Wih1 : Whh1;

  // LDS: W kt 5,6,7 (144 frags, 144KB)
  for (int idx = tid; idx < 144 * 64; idx += 512) {
    int f = idx >> 6, lf = idx & 63;
    int nt = f / 3, kk = 5 + (f % 3);
    *(f16x8*)&lds[f * 512 + lf * 8] =
        cvt8(&Wm[(nt * 16 + (lf & 15)) * 256 + kk * 32 + (lf >> 4) * 8]);
  }
  for (int idx = tid; idx < 2 * 4096; idx += 512) hring[idx] = (f16)0.f;

  // regs: W kt 0..4  -> wfr[(g*2+tt)*5 + kt]   (30 frags = 120 VGPR)
  f16x8 wfr[30];
#pragma unroll
  for (int g = 0; g < 3; ++g)
#pragma unroll
    for (int tt = 0; tt < 2; ++tt) {
      int row = g * 256 + 32 * wv + 16 * tt + lrow;
#pragma unroll
      for (int kt = 0; kt < 5; ++kt)
        wfr[(g * 2 + tt) * 5 + kt] = cvt8(&Wm[row * 256 + kt * 32 + lgrp * 8]);
    }
#define WL(g, tt, kt) \
  (*(const f16x8*)&lds[((((g)*16 + wv * 2 + (tt)) * 3) + ((kt)-5)) * 512 + lane * 8])
#define WF(g, tt, kt) wfr[((g)*2 + (tt)) * 5 + (kt)]

  // ---- XCD placement verification -> global fast/slow decision ----
  {
    unsigned xcc;
    asm volatile("s_getreg_b32 %0, hwreg(HW_REG_XCC_ID)" : "=s"(xcc));
    if (tid == 0) st_sys(ids + bx, (int)xcc + 1);
    if (bx == 0 && wv == 0) {
      int ok, guard = 0;
      for (;;) {
        int v0 = ld_sys(ids + lane), v1 = ld_sys(ids + 64 + lane);
        int v2 = ld_sys(ids + 128 + lane), v3 = ld_sys(ids + 192 + lane);
        ok = (v0 && v1 && v2 && v3);
        if (__all(ok)) { ok = 1; break; }
        if (++guard > (1 << 16)) { ok = 0; break; }
        __builtin_amdgcn_s_sleep(8);
      }
      int verdict = 1;
      if (ok) {
        int r0 = ld_sys(ids + lane), r1 = ld_sys(ids + 64 + lane);
        int r2 = ld_sys(ids + 128 + lane), r3 = ld_sys(ids + 192 + lane);
        int eq = (r1 == r0) && (r2 == r0) && (r3 == r0);
        verdict = __all(eq) ? 2 : 1;
      }
      if (lane == 0) st_sys(dec, verdict);
    }
  }
  int decision = 1;
  {
    int g = 0;
    for (;;) {
      int d = ld_sys(dec);
      if (d) { decision = d; break; }
      if (++g > (1 << 20)) break;
      __builtin_amdgcn_s_sleep(8);
    }
  }
  __syncthreads();

  int* fbase = flags + c * 64;
  int dead = 0;

  if (stage == 0) {
    // ============================ L0 ============================
    f16x8 wx[6];
#pragma unroll
    for (int g = 0; g < 3; ++g)
#pragma unroll
      for (int tt = 0; tt < 2; ++tt) {
        int row = g * 256 + 32 * wv + 16 * tt + lrow;
        f16 v[8];
#pragma unroll
        for (int j = 0; j < 8; ++j) {
          int k = lgrp * 8 + j;
          v[j] = (k < I_) ? (f16)Wih0[row * I_ + k] : (f16)0.f;
        }
        wx[g * 2 + tt] = *(f16x8*)v;
      }
    float bR[2], bZ[2], bI[2], bH[2];
#pragma unroll
    for (int tt = 0; tt < 2; ++tt) {
      int col = 32 * wv + 16 * tt + lrow;
      bR[tt] = bih0[col] + bhh0[col];
      bZ[tt] = bih0[256 + col] + bhh0[256 + col];
      bI[tt] = bih0[512 + col];
      bH[tt] = bhh0[512 + col];
    }
    float h0r[2][4] = {{0.f, 0.f, 0.f, 0.f}, {0.f, 0.f, 0.f, 0.f}};
    const float* xrow = x + (size_t)(c * 16 + lrow) * T_ * I_;
    const int o1 = (lgrp == 0) ? 0 : (lgrp == 1) ? 8 : (lgrp == 2) ? 14 : 0;
    const int o2 = (lgrp == 0) ? 4 : (lgrp == 1) ? 12 : 0;
    int* fpost = fbase + wv;                          // fh0
    const int* fcred0 = fbase + 24 + (lane & 7);      // fg1p even; +8 for odd

    auto loop0 = [&](auto FC) {
      constexpr bool F = decltype(FC)::value;
      f32x4 xa1 = ldx4(xrow + o1), xa2 = ldx4(xrow + o2);              // x(0)
      f32x4 xb1 = ldx4(xrow + I_ + o1), xb2 = ldx4(xrow + I_ + o2);    // x(1)
      asm volatile("s_waitcnt vmcnt(0)" ::: "memory");
      SB();
      auto body = [&](int t, f32x4& x1, f32x4& x2) {
        f16x8 ax;
        {
          float s0 = (lgrp == 2) ? x1[2] : x1[0];
          float s1 = (lgrp == 2) ? x1[3] : x1[1];
          ax[0] = (f16)s0;    ax[1] = (f16)s1;
          ax[2] = (f16)x1[2]; ax[3] = (f16)x1[3];
          ax[4] = (f16)x2[0]; ax[5] = (f16)x2[1];
          ax[6] = (f16)x2[2]; ax[7] = (f16)x2[3];
        }
        f32x4 aR[2], aZ[2], aI[2], aH[2];
#pragma unroll
        for (int tt = 0; tt < 2; ++tt) {
          aR[tt] = (f32x4){bR[tt], bR[tt], bR[tt], bR[tt]};
          aZ[tt] = (f32x4){bZ[tt], bZ[tt], bZ[tt], bZ[tt]};
          aI[tt] = (f32x4){bI[tt], bI[tt], bI[tt], bI[tt]};
          aH[tt] = (f32x4){bH[tt], bH[tt], bH[tt], bH[tt]};
          aR[tt] = MFMA16(ax, wx[0 * 2 + tt], aR[tt]);
          aZ[tt] = MFMA16(ax, wx[1 * 2 + tt], aZ[tt]);
          aI[tt] = MFMA16(ax, wx[2 * 2 + tt], aI[tt]);
        }
        const f16* ha = &hring[((t + 1) & 1) * 4096 + lane * 8];
#pragma unroll
        for (int kt = 0; kt < 8; ++kt) {
          f16x8 a = *(const f16x8*)(ha + kt * 512);
#pragma unroll
          for (int tt = 0; tt < 2; ++tt) {
            f16x8 br = (kt < 5) ? WF(0, tt, kt) : WL(0, tt, kt);
            f16x8 bz = (kt < 5) ? WF(1, tt, kt) : WL(1, tt, kt);
            f16x8 bn = (kt < 5) ? WF(2, tt, kt) : WL(2, tt, kt);
            aR[tt] = MFMA16(a, br, aR[tt]);
            aZ[tt] = MFMA16(a, bz, aZ[tt]);
            aH[tt] = MFMA16(a, bn, aH[tt]);
          }
        }
#pragma unroll
        for (int tt = 0; tt < 2; ++tt)
#pragma unroll
          for (int i = 0; i < 4; ++i) {
            float rr = sigm(aR[tt][i]);
            float zz = sigm(aZ[tt][i]);
            float nn = tanh_fast(aI[tt][i] + rr * aH[tt][i]);
            h0r[tt][i] = (1.f - zz) * nn + zz * h0r[tt][i];
            int off = wv * 512 +
                      ((lgrp * 4 + i) + 16 * (2 * tt + (lrow >> 3))) * 8 +
                      (lrow & 7);
            hring[(t & 1) * 4096 + off] = (f16)h0r[tt][i];
          }
        f16x8 own = *(const f16x8*)&hring[(t & 1) * 4096 + wv * 512 + lane * 8];
        // credit: GI1(parity t&1) consumed h0(t-4)  (fg1p >= t-3)
        if (!dead) {
          const int* fc = fcred0 + ((t & 1) << 3);
          int tgt = t - 3, guard = 0;
          for (;;) {
            int v = ldf<F>(fc);
            if (__all(v >= tgt)) break;
            if (++guard > GUARD) { dead = 1; break; }
          }
        }
        SB();
        stg16<F>(hb0 + (size_t)(((t & 3) * 64 + c) * 8 + wv) * 512 + lane * 8, own);
        {
          int tn = (t + 2 < T_) ? t + 2 : t;
          const float* px = xrow + (size_t)tn * I_;
          x1 = ldx4(px + o1);
          x2 = ldx4(px + o2);
        }
        __syncthreads();
        asm volatile("s_waitcnt vmcnt(2)" ::: "memory");  // publish ack'd
        SB();
        if (lane == 0) stf<F>(fpost, t + 1);
      };
      for (int t = 0; t < T_; t += 2) {
        body(t, xa1, xa2);
        body(t + 1, xb1, xb2);
      }
    };
    if (decision == 2) loop0(TrueT{});
    else loop0(FalseT{});
  } else if (stage == 1) {
    // ============================ GI1 (parity split) ============================
    float bR[2], bZ[2], bI[2];
#pragma unroll
    for (int tt = 0; tt < 2; ++tt) {
      int col = 32 * wv + 16 * tt + lrow;
      bR[tt] = bih1[col];
      bZ[tt] = bih1[256 + col];
      bI[tt] = bih1[512 + col];
    }
    // combined poll: lanes with bit4 check fh1p (grp5), others fh0 (grp0)
    const int* fpoll = fbase + ((lane & 16) ? 40 : 0) + (lane & 7);
    int* fpost_p = fbase + 24 + 8 * par + wv;  // fg1p[par]
    int* fpost_d = fbase + 8 + 8 * par + wv;   // fgi[par]

    auto loop1 = [&](auto FC) {
      constexpr bool F = decltype(FC)::value;
      for (int t = par; t < T_; t += 2) {
        if (!dead) {
          int guard = 0;
          for (;;) {
            int v = ldf<F>(fpoll);
            int tgt = (lane & 16) ? (t - 3) : (t + 1);
            if (__all(v >= tgt)) break;
            if (++guard > GUARD) { dead = 1; break; }
          }
        }
        SB();
        const f16* hb = hb0 + (size_t)((t & 3) * 64 + c) * 4096 + lane * 8;
        f16x8 ah[8];
#pragma unroll
        for (int kt = 0; kt < 8; ++kt) ah[kt] = ldh<F>(hb + kt * 512);
        SB();
        f32x4 aR[2], aZ[2], aI[2];
#pragma unroll
        for (int tt = 0; tt < 2; ++tt) {
          aR[tt] = (f32x4){bR[tt], bR[tt], bR[tt], bR[tt]};
          aZ[tt] = (f32x4){bZ[tt], bZ[tt], bZ[tt], bZ[tt]};
          aI[tt] = (f32x4){bI[tt], bI[tt], bI[tt], bI[tt]};
        }
        asm volatile("s_waitcnt vmcnt(4)" ::: "memory");  // ah[0..3]
        SB();
#pragma unroll
        for (int kt = 0; kt < 4; ++kt)
#pragma unroll
          for (int tt = 0; tt < 2; ++tt) {
            aR[tt] = MFMA16(ah[kt], WF(0, tt, kt), aR[tt]);
            aZ[tt] = MFMA16(ah[kt], WF(1, tt, kt), aZ[tt]);
            aI[tt] = MFMA16(ah[kt], WF(2, tt, kt), aI[tt]);
          }
        asm volatile("s_waitcnt vmcnt(0)" ::: "memory");  // ah all in regs
        SB();
        if (lane == 0) stf<F>(fpost_p, t + 1);  // h0(t) consumed
#pragma unroll
        for (int kt = 4; kt < 8; ++kt)
#pragma unroll
          for (int tt = 0; tt < 2; ++tt) {
            f16x8 br = (kt < 5) ? WF(0, tt, kt) : WL(0, tt, kt);
            f16x8 bz = (kt < 5) ? WF(1, tt, kt) : WL(1, tt, kt);
            f16x8 bn = (kt < 5) ? WF(2, tt, kt) : WL(2, tt, kt);
            aR[tt] = MFMA16(ah[kt], br, aR[tt]);
            aZ[tt] = MFMA16(ah[kt], bz, aZ[tt]);
            aI[tt] = MFMA16(ah[kt], bn, aI[tt]);
          }
        f16* gbase = gb1 + (size_t)((t & 3) * 64 + c) * 12288 + lane * 4;
#pragma unroll
        for (int g = 0; g < 3; ++g)
#pragma unroll
          for (int tt = 0; tt < 2; ++tt) {
            int nt = g * 16 + wv * 2 + tt;
            f32x4 a = (g == 0) ? aR[tt] : (g == 1) ? aZ[tt] : aI[tt];
            f16x4 v;
            v[0] = (f16)a[0]; v[1] = (f16)a[1]; v[2] = (f16)a[2]; v[3] = (f16)a[3];
            stg8<F>(gbase + nt * 256, v);
          }
        asm volatile("s_waitcnt vmcnt(0)" ::: "memory");
        SB();
        if (lane == 0) stf<F>(fpost_d, t + 1);
      }
    };
    if (decision == 2) loop1(TrueT{});
    else loop1(FalseT{});
  } else {
    // ============================ HH1 ============================
    float bR[2], bZ[2], bH[2];
#pragma unroll
    for (int tt = 0; tt < 2; ++tt) {
      int col = 32 * wv + 16 * tt + lrow;
      bR[tt] = bhh1[col];
      bZ[tt] = bhh1[256 + col];
      bH[tt] = bhh1[512 + col];
    }
    float h1r[2][4] = {{0.f, 0.f, 0.f, 0.f}, {0.f, 0.f, 0.f, 0.f}};
    const int* fpoll0 = fbase + 8 + (lane & 7);  // fgi even; +8 odd
    int* fpost = fbase + 40 + wv;                // fh1p

    auto loop2 = [&](auto FC) {
      constexpr bool F = decltype(FC)::value;
      for (int t = 0; t < T_; ++t) {
        if (!dead) {
          const int* fp = fpoll0 + ((t & 1) << 3);
          int guard = 0;
          for (;;) {
            int v = ldf<F>(fp);
            if (__all(v >= t + 1)) break;
            if (++guard > GUARD) { dead = 1; break; }
          }
        }
        SB();
        const f16* gbase = gb1 + (size_t)((t & 3) * 64 + c) * 12288 + lane * 4;
        f16x4 gi[6];
#pragma unroll
        for (int g = 0; g < 3; ++g)
#pragma unroll
          for (int tt = 0; tt < 2; ++tt)
            gi[g * 2 + tt] = ldg8<F>(gbase + (g * 16 + wv * 2 + tt) * 256);
        SB();
        f32x4 aR[2], aZ[2], aH[2];
#pragma unroll
        for (int tt = 0; tt < 2; ++tt) {
          aR[tt] = (f32x4){bR[tt], bR[tt], bR[tt], bR[tt]};
          aZ[tt] = (f32x4){bZ[tt], bZ[tt], bZ[tt], bZ[tt]};
          aH[tt] = (f32x4){bH[tt], bH[tt], bH[tt], bH[tt]};
        }
        const f16* ha = &hring[((t + 1) & 1) * 4096 + lane * 8];
#pragma unroll
        for (int kt = 0; kt < 8; ++kt) {
          f16x8 a = *(const f16x8*)(ha + kt * 512);
#pragma unroll
          for (int tt = 0; tt < 2; ++tt) {
            f16x8 br = (kt < 5) ? WF(0, tt, kt) : WL(0, tt, kt);
            f16x8 bz = (kt < 5) ? WF(1, tt, kt) : WL(1, tt, kt);
            f16x8 bn = (kt < 5) ? WF(2, tt, kt) : WL(2, tt, kt);
            aR[tt] = MFMA16(a, br, aR[tt]);
            aZ[tt] = MFMA16(a, bz, aZ[tt]);
            aH[tt] = MFMA16(a, bn, aH[tt]);
          }
        }
        asm volatile("s_waitcnt vmcnt(0)" ::: "memory");  // gi landed
        SB();
        if (lane == 0) stf<F>(fpost, t + 1);  // gi(t) consumed
#pragma unroll
        for (int tt = 0; tt < 2; ++tt)
#pragma unroll
          for (int i = 0; i < 4; ++i) {
            float rr = sigm((float)gi[0 * 2 + tt][i] + aR[tt][i]);
            float zz = sigm((float)gi[1 * 2 + tt][i] + aZ[tt][i]);
            float nn = tanh_fast((float)gi[2 * 2 + tt][i] + rr * aH[tt][i]);
            h1r[tt][i] = (1.f - zz) * nn + zz * h1r[tt][i];
            int off = wv * 512 +
                      ((lgrp * 4 + i) + 16 * (2 * tt + (lrow >> 3))) * 8 +
                      (lrow & 7);
            hring[(t & 1) * 4096 + off] = (f16)h1r[tt][i];
          }
        __syncthreads();
      }
    };
    if (decision == 2) loop2(TrueT{});
    else loop2(FalseT{});

    // ---- fc head ----
    float fw0 = fcw[32 * wv + lrow], fw1 = fcw[32 * wv + 16 + lrow];
    float* red = (float*)lds;
    __syncthreads();
#pragma unroll
    for (int i = 0; i < 4; ++i) {
      float v = h1r[0][i] * fw0 + h1r[1][i] * fw1;
#pragma unroll
      for (int m = 1; m < 16; m <<= 1) v += __shfl_xor(v, m);
      if (lrow == 0) red[wv * 16 + lgrp * 4 + i] = v;
    }
    __syncthreads();
    if (tid < 16) {
      float s = fcb[0];
#pragma unroll
      for (int w2 = 0; w2 < 8; ++w2) s += red[w2 * 16 + tid];
      out[c * 16 + tid] = s;
    }
  }
}

extern "C" void kernel_launch(void* const* d_in, const int* in_sizes, int n_in,
                              void* d_out, int out_size, void* d_ws, size_t ws_size,
                              hipStream_t stream) {
  const float* x    = (const float*)d_in[0];
  const float* Wih0 = (const float*)d_in[1];
  const float* Whh0 = (const float*)d_in[2];
  const float* bih0 = (const float*)d_in[3];
  const float* bhh0 = (const float*)d_in[4];
  const float* Wih1 = (const float*)d_in[5];
  const float* Whh1 = (const float*)d_in[6];
  const float* bih1 = (const float*)d_in[7];
  const float* bhh1 = (const float*)d_in[8];
  const float* fcw  = (const float*)d_in[9];
  const float* fcb  = (const float*)d_in[10];

  f16* hb0 = (f16*)d_ws;
  f16* gb1 = hb0 + (size_t)HB0_ELEMS;
  int* flags = (int*)(gb1 + (size_t)GB1_ELEMS);
  int* ids = flags + NFLAGS;
  int* dec = ids + 256;

  hipFuncSetAttribute((const void*)gru_main,
                      hipFuncAttributeMaxDynamicSharedMemorySize, LDS_BYTES);

  init_ws<<<32, 256, 0, stream>>>(flags);
  gru_main<<<256, 512, LDS_BYTES, stream>>>(
      x, Wih0, Whh0, Wih1, Whh1, bih0, bhh0, bih1, bhh1, fcw, fcb, hb0, gb1,
      flags, ids, dec, (float*)d_out);
}

// Round 12
// 2620.460 us; speedup vs baseline: 1.1376x; 1.1376x over previous
//
#include <hip/hip_runtime.h>

#define T_ 1024
#define I_ 18
#define GUARD (1 << 18)
#define H_SLOT (16 * 32 * 512)  // 262144 f16 = 512KB per ring slot
#define NFLAGS (16 * 4 * 32)
#define INST_F16 ((size_t)6 * H_SLOT + 40960)

typedef _Float16 f16;
typedef _Float16 f16x8 __attribute__((ext_vector_type(8)));
typedef float f32x4 __attribute__((ext_vector_type(4)));

#define MFMA16(a, b, c) __builtin_amdgcn_mfma_f32_16x16x32_f16((a), (b), (c), 0, 0, 0)
#define SB() __builtin_amdgcn_sched_barrier(0)
// fragment offset: slot, chunk(16), kt(8), m(4) -> 512-f16 frags
#define FR(s, ch, kt, m) ((((size_t)(s)*16 + (ch)) * 32 + (kt)*4 + (m)) * 512)

struct TrueT { static constexpr bool value = true; };
struct FalseT { static constexpr bool value = false; };

__global__ void init_ws(f16* __restrict__ hb, int* __restrict__ flg) {
  int i = blockIdx.x * blockDim.x + threadIdx.x;
  unsigned* p = (unsigned*)hb;  // hb0(4 slots)+hb1(2 slots) = 3*H_SLOT uints
  for (int k = i; k < 3 * H_SLOT; k += gridDim.x * blockDim.x) p[k] = 0u;
  if (i < NFLAGS + 256 + 8) flg[i] = 0;  // flags | ids | dec
}

__device__ __forceinline__ float sigm(float v) {
  return __builtin_amdgcn_rcpf(1.f + __expf(-v));
}
__device__ __forceinline__ float tanh_fast(float v) {
  v = fmaxf(v, -15.f);
  float e = __expf(-2.f * v);
  return (1.f - e) * __builtin_amdgcn_rcpf(1.f + e);
}
__device__ __forceinline__ f16x8 cvt8(const float* q) {
  const f32x4* a = (const f32x4*)q;
  f32x4 u = a[0], v = a[1];
  f16x8 r;
  r[0] = (f16)u[0]; r[1] = (f16)u[1]; r[2] = (f16)u[2]; r[3] = (f16)u[3];
  r[4] = (f16)v[0]; r[5] = (f16)v[1]; r[6] = (f16)v[2]; r[7] = (f16)v[3];
  return r;
}

// FAST = XCD-local L2 (plain stores, nt loads). slow = sc0 sc1 MALL-coherent.
template <bool FAST>
__device__ __forceinline__ f16x8 ldh(const f16* p) {
  f16x8 r;
  if (FAST) asm volatile("global_load_dwordx4 %0, %1, off nt" : "=&v"(r) : "v"(p));
  else asm volatile("global_load_dwordx4 %0, %1, off sc0 sc1" : "=&v"(r) : "v"(p));
  return r;
}
template <bool FAST>
__device__ __forceinline__ void sth(f16* p, f16 v) {
  unsigned u = (unsigned)__builtin_bit_cast(unsigned short, v);
  if (FAST) asm volatile("global_store_short %0, %1, off" ::"v"(p), "v"(u) : "memory");
  else asm volatile("global_store_short %0, %1, off sc0 sc1" ::"v"(p), "v"(u) : "memory");
}
template <bool FAST>
__device__ __forceinline__ void stf(int* p, int v) {
  if (FAST) asm volatile("global_store_dword %0, %1, off" ::"v"(p), "v"(v) : "memory");
  else asm volatile("global_store_dword %0, %1, off sc0 sc1" ::"v"(p), "v"(v) : "memory");
}
template <bool FAST>
__device__ __forceinline__ int ldf(const int* p) {  // flag load + full drain
  int r;
  if (FAST)
    asm volatile("global_load_dword %0, %1, off nt\n\ts_waitcnt vmcnt(0)"
                 : "=&v"(r) : "v"(p) : "memory");
  else
    asm volatile("global_load_dword %0, %1, off sc0 sc1\n\ts_waitcnt vmcnt(0)"
                 : "=&v"(r) : "v"(p) : "memory");
  return r;
}
__device__ __forceinline__ int ld_sys(const int* p) {
  int r;
  asm volatile("global_load_dword %0, %1, off sc0 sc1\n\ts_waitcnt vmcnt(0)"
               : "=&v"(r) : "v"(p) : "memory");
  return r;
}
__device__ __forceinline__ void st_sys(int* p, int v) { stf<false>(p, v); }
__device__ __forceinline__ f32x4 ldx4(const float* p) {
  f32x4 r;
  asm volatile("global_load_dwordx4 %0, %1, off" : "=&v"(r) : "v"(p));
  return r;
}

// 256 blocks x 512 threads, 1 block/CU (96KB LDS: 24KB whh1 + 72KB dyn pad).
// chunk = bx&15 (rows chunk*64..+64), slice = bx>>4 (cols slice*16..+16).
// waves 0-3 = L0 recurrence (critical), waves 4-7 = L1 (trails 1 phase).
// MODE 0 = full protocol. MODE 1 = L0 only (L1 waves idle). MODE 2 = no sync.
template <int MODE, int T>
__global__ void __launch_bounds__(512)
__attribute__((amdgpu_waves_per_eu(2, 2))) gru_main(
    const float* __restrict__ x, const float* __restrict__ Wih0,
    const float* __restrict__ Whh0, const float* __restrict__ Wih1,
    const float* __restrict__ Whh1, const float* __restrict__ bih0,
    const float* __restrict__ bhh0, const float* __restrict__ bih1,
    const float* __restrict__ bhh1, const float* __restrict__ fcw,
    f16* __restrict__ hb0, f16* __restrict__ hb1, float* __restrict__ part,
    int* __restrict__ flags, int* __restrict__ ids, int* __restrict__ dec) {
  __shared__ f16 whh1_l[24 * 512];  // 24KB W_hh1 slice fragments (L1 B-op)

  const int tid = threadIdx.x;
  const int wv = tid >> 6, lane = tid & 63;
  const int w = wv & 3;
  const bool isL0 = wv < 4;
  const int lrow = lane & 15, lgrp = lane >> 4;
  const int chunk = blockIdx.x & 15, slice = blockIdx.x >> 4;
  const int c = slice * 16 + lrow;

  for (int idx = tid; idx < 24 * 64; idx += 512) {
    int f = idx >> 6, l = idx & 63;
    int g = f >> 3, kt = f & 7;
    int n = g * 256 + slice * 16 + (l & 15);
    ((f16x8*)whh1_l)[idx] = cvt8(&Whh1[n * 256 + kt * 32 + (l >> 4) * 8]);
  }

  const int* fpoll = flags + (chunk * 4 + w) * 32 + (lane & 31);
  const int rbase = chunk * 64 + w * 16;
  const int s_kt = slice >> 1;
  const int s_off = 128 * ((slice & 1) * 2 + (lrow >> 3)) + (lrow & 7);

  // ---- runtime XCD-placement verification -> global fast/slow decision ----
  {
    unsigned xcc;
    asm volatile("s_getreg_b32 %0, hwreg(HW_REG_XCC_ID)" : "=s"(xcc));
    if (tid == 0) st_sys(ids + blockIdx.x, (int)xcc + 1);
    if (blockIdx.x == 0 && wv == 0) {
      int ok, guard = 0;
      for (;;) {
        int v0 = ld_sys(ids + lane * 4 + 0), v1 = ld_sys(ids + lane * 4 + 1);
        int v2 = ld_sys(ids + lane * 4 + 2), v3 = ld_sys(ids + lane * 4 + 3);
        ok = (v0 && v1 && v2 && v3);
        if (__all(ok)) { ok = 1; break; }
        if (++guard > (1 << 16)) { ok = 0; break; }
        __builtin_amdgcn_s_sleep(8);
      }
      int verdict = 1;
      if (ok) {
        int eq = 1;
        if (lane < 16) {  // blocks of chunk (=lane): slice*16 + lane
          int r0 = ld_sys(ids + lane);
          for (int s = 1; s < 16; ++s) eq &= (ld_sys(ids + s * 16 + lane) == r0);
        }
        verdict = __all(eq) ? 2 : 1;
      }
      if (lane == 0) st_sys(dec, verdict);
    }
  }
  int decision = 1;
  {
    int g = 0;
    for (;;) {
      int d = ld_sys(dec);
      if (d) { decision = d; break; }
      if (++g > (1 << 20)) break;
      __builtin_amdgcn_s_sleep(8);
    }
  }
  __syncthreads();  // LDS ready; only block-wide barrier
  int dead = 0;

  if (isL0) {
    // =========================== LAYER-0 WAVES ===========================
    f16x8 wfA[27];  // ih0(3) + hh0(24)
#pragma unroll
    for (int g = 0; g < 3; ++g) {
      int n = g * 256 + c;
      f16 v[8];
#pragma unroll
      for (int j = 0; j < 8; ++j) {
        int k = lgrp * 8 + j;
        v[j] = (k < I_) ? (f16)Wih0[n * I_ + k] : (f16)0.f;
      }
      wfA[g] = *(f16x8*)v;
    }
#pragma unroll
    for (int g = 0; g < 3; ++g)
#pragma unroll
      for (int kt = 0; kt < 8; ++kt)
        wfA[3 + g * 8 + kt] = cvt8(&Whh0[(g * 256 + c) * 256 + kt * 32 + lgrp * 8]);

    const float bR0 = bih0[c] + bhh0[c], bZ0 = bih0[256 + c] + bhh0[256 + c];
    const float bI0 = bih0[512 + c], bH0 = bhh0[512 + c];
    float h0r[4] = {0.f, 0.f, 0.f, 0.f};
    int* fpost0 = flags + (chunk * 4 + w) * 32 + slice;
    const float* xrow = x + (size_t)(rbase + lrow) * T_ * I_;
    const int o1 = (lgrp == 0) ? 0 : (lgrp == 1) ? 8 : (lgrp == 2) ? 14 : 0;
    const int o2 = (lgrp == 0) ? 4 : (lgrp == 1) ? 12 : 0;

    auto loop0 = [&](auto FC) {
      constexpr bool F = decltype(FC)::value;
      f32x4 xa1 = ldx4(xrow + o1), xa2 = ldx4(xrow + o2);            // x(0)
      f32x4 xb1 = ldx4(xrow + I_ + o1), xb2 = ldx4(xrow + I_ + o2);  // x(1)
      asm volatile("s_waitcnt vmcnt(0)" ::: "memory");
      SB();
      auto body = [&](int p, f32x4& X1, f32x4& X2) {
        if (MODE == 2) {
          asm volatile("s_waitcnt vmcnt(0)" ::: "memory");  // count baseline
        } else if (p > 0 && !dead) {
          // flag0 >= p (peers' h0(p-1)); flag1 >= p-3 (hb0 ring-4 safety).
          // x(p) was issued ~1 full phase ago -> drain inside ldf is free.
          int guard = 0;
          for (;;) {
            int v = ldf<F>(fpoll);
            int tgt = (lane & 16) ? (p - (MODE == 1 ? (1 << 20) : 3)) : p;
            if (__all(v >= tgt)) break;
            if (++guard > GUARD) { dead = 1; break; }
          }
        }
        SB();
        f16x8 ah0[8];
        {
          const f16* b0 = hb0 + FR((p - 1) & 3, chunk, 0, w) + lane * 8;
#pragma unroll
          for (int kt = 0; kt < 8; ++kt) ah0[kt] = ldh<F>(b0 + kt * 2048);
        }
        SB();
        f16x8 ax;  // x-only deps: assemble + ih0 MFMAs overlap ah0 flight
        {
          float s0 = (lgrp == 2) ? X1[2] : X1[0];
          float s1 = (lgrp == 2) ? X1[3] : X1[1];
          ax[0] = (f16)s0;    ax[1] = (f16)s1;
          ax[2] = (f16)X1[2]; ax[3] = (f16)X1[3];
          ax[4] = (f16)X2[0]; ax[5] = (f16)X2[1];
          ax[6] = (f16)X2[2]; ax[7] = (f16)X2[3];
        }
        f32x4 aR = {bR0, bR0, bR0, bR0}, aZ = {bZ0, bZ0, bZ0, bZ0};
        f32x4 aI = {bI0, bI0, bI0, bI0}, aH = {bH0, bH0, bH0, bH0};
        aR = MFMA16(ax, wfA[0], aR);
        aZ = MFMA16(ax, wfA[1], aZ);
        aI = MFMA16(ax, wfA[2], aI);
        SB();
        asm volatile("s_waitcnt vmcnt(4)" ::: "memory");  // ah0[0..3]
        SB();
#pragma unroll
        for (int kt = 0; kt < 4; ++kt) {
          aR = MFMA16(ah0[kt], wfA[3 + kt], aR);
          aZ = MFMA16(ah0[kt], wfA[11 + kt], aZ);
          aH = MFMA16(ah0[kt], wfA[19 + kt], aH);
        }
        SB();
        asm volatile("s_waitcnt vmcnt(0)" ::: "memory");  // ah0[4..7]
        SB();
#pragma unroll
        for (int kt = 4; kt < 8; ++kt) {
          aR = MFMA16(ah0[kt], wfA[3 + kt], aR);
          aZ = MFMA16(ah0[kt], wfA[11 + kt], aZ);
          aH = MFMA16(ah0[kt], wfA[19 + kt], aH);
        }
        {
          f16* d0 = hb0 + FR(p & 3, chunk, s_kt, w) + s_off;
#pragma unroll
          for (int i = 0; i < 4; ++i) {
            float rr = sigm(aR[i]);
            float zz = sigm(aZ[i]);
            float nn = tanh_fast(aI[i] + rr * aH[i]);
            h0r[i] = (1.f - zz) * nn + zz * h0r[i];
            sth<F>(d0 + (lgrp * 4 + i) * 8, (f16)h0r[i]);
          }
        }
        SB();
        asm volatile("s_waitcnt vmcnt(0)" ::: "memory");  // only h0 acks
        SB();
        if (lane == 0) stf<F>(fpost0, p + 1);
        {  // x(p+2): full phase of lead time before any drain can touch it
          int tn = (p + 2 < T) ? p + 2 : T - 1;
          const float* px = xrow + (size_t)tn * I_;
          X1 = ldx4(px + o1);
          X2 = ldx4(px + o2);
        }
      };
      for (int p = 0; p < T; p += 2) {
        body(p, xa1, xa2);
        body(p + 1, xb1, xb2);
      }
    };
    if (decision == 2) loop0(TrueT{});
    else loop0(FalseT{});
  } else {
    // =========================== LAYER-1 WAVES ===========================
    if (MODE == 1) return;  // SOLO ablation: L0-only system
    f16x8 wfB[24];          // ih1
#pragma unroll
    for (int g = 0; g < 3; ++g)
#pragma unroll
      for (int kt = 0; kt < 8; ++kt)
        wfB[g * 8 + kt] = cvt8(&Wih1[(g * 256 + c) * 256 + kt * 32 + lgrp * 8]);

    const float bR1 = bih1[c] + bhh1[c], bZ1 = bih1[256 + c] + bhh1[256 + c];
    const float bI1 = bih1[512 + c], bH1 = bhh1[512 + c];
    const float fw = fcw[c];
    float h1r[4] = {0.f, 0.f, 0.f, 0.f};
    int* fpost1 = flags + (chunk * 4 + w) * 32 + 16 + slice;

    auto loop1 = [&](auto FC) {
      constexpr bool F = decltype(FC)::value;
      for (int p = 1; p <= T; ++p) {
        // single combined poll: flag0 >= p AND flag1 >= p-1
        if (MODE == 2) {
          asm volatile("s_waitcnt vmcnt(0)" ::: "memory");
        } else if (!dead) {
          int guard = 0;
          for (;;) {
            int v = ldf<F>(fpoll);
            int tgt = (lane & 16) ? (p - 1) : p;
            if (__all(v >= tgt)) break;
            if (++guard > GUARD) { dead = 1; break; }
          }
        }
        SB();
        f16x8 ah1[8], ah0[8];
        {
          const f16* b1 = hb1 + FR(p & 1, chunk, 0, w) + lane * 8;
#pragma unroll
          for (int kt = 0; kt < 8; ++kt) ah1[kt] = ldh<F>(b1 + kt * 2048);
          const f16* b0 = hb0 + FR((p - 1) & 3, chunk, 0, w) + lane * 8;
#pragma unroll
          for (int kt = 0; kt < 8; ++kt) ah0[kt] = ldh<F>(b0 + kt * 2048);
        }
        SB();
        asm volatile("s_waitcnt vmcnt(8)" ::: "memory");  // ah1 done
        SB();
        f32x4 aR = {bR1, bR1, bR1, bR1}, aZ = {bZ1, bZ1, bZ1, bZ1};
        f32x4 aI = {bI1, bI1, bI1, bI1}, aH = {bH1, bH1, bH1, bH1};
#pragma unroll
        for (int kt = 0; kt < 8; ++kt) {  // hh1 (LDS B) while ah0 flies
          f16x8 br = *(const f16x8*)&whh1_l[(0 * 8 + kt) * 512 + lane * 8];
          f16x8 bz = *(const f16x8*)&whh1_l[(1 * 8 + kt) * 512 + lane * 8];
          f16x8 bn = *(const f16x8*)&whh1_l[(2 * 8 + kt) * 512 + lane * 8];
          aR = MFMA16(ah1[kt], br, aR);
          aZ = MFMA16(ah1[kt], bz, aZ);
          aH = MFMA16(ah1[kt], bn, aH);
        }
        SB();
        asm volatile("s_waitcnt vmcnt(0)" ::: "memory");  // ah0 done
        SB();
#pragma unroll
        for (int kt = 0; kt < 8; ++kt) {
          aR = MFMA16(ah0[kt], wfB[kt], aR);
          aZ = MFMA16(ah0[kt], wfB[8 + kt], aZ);
          aI = MFMA16(ah0[kt], wfB[16 + kt], aI);
        }
        {
          f16* d1 = hb1 + FR((p - 1) & 1, chunk, s_kt, w) + s_off;
#pragma unroll
          for (int i = 0; i < 4; ++i) {
            float rr = sigm(aR[i]);
            float zz = sigm(aZ[i]);
            float nn = tanh_fast(aI[i] + rr * aH[i]);
            h1r[i] = (1.f - zz) * nn + zz * h1r[i];
            sth<F>(d1 + (lgrp * 4 + i) * 8, (f16)h1r[i]);
          }
        }
        SB();
        asm volatile("s_waitcnt vmcnt(0)" ::: "memory");  // store acks
        SB();
        if (lane == 0) stf<F>(fpost1, p);
      }
    };
    if (decision == 2) loop1(TrueT{});
    else loop1(FalseT{});

    // ---- fc head partials ----
    float tmp[4];
#pragma unroll
    for (int i = 0; i < 4; ++i) {
      float v = h1r[i] * fw;
#pragma unroll
      for (int m = 1; m < 16; m <<= 1) v += __shfl_xor(v, m);
      tmp[i] = v;
    }
    if (lrow == 0) {
#pragma unroll
      for (int i = 0; i < 4; ++i)
        part[(size_t)(rbase + lgrp * 4 + i) * 16 + slice] = tmp[i];
    }
  }
}

__global__ void fc_reduce(const float* __restrict__ part,
                          const float* __restrict__ fcb,
                          float* __restrict__ out) {
  int r = blockIdx.x * blockDim.x + threadIdx.x;
  if (r < 1024) {
    float s = fcb[0];
#pragma unroll
    for (int i = 0; i < 16; ++i) s += part[r * 16 + i];
    out[r] = s;
  }
}

extern "C" void kernel_launch(void* const* d_in, const int* in_sizes, int n_in,
                              void* d_out, int out_size, void* d_ws, size_t ws_size,
                              hipStream_t stream) {
  const float* x    = (const float*)d_in[0];
  const float* Wih0 = (const float*)d_in[1];
  const float* Whh0 = (const float*)d_in[2];
  const float* bih0 = (const float*)d_in[3];
  const float* bhh0 = (const float*)d_in[4];
  const float* Wih1 = (const float*)d_in[5];
  const float* Whh1 = (const float*)d_in[6];
  const float* bih1 = (const float*)d_in[7];
  const float* bhh1 = (const float*)d_in[8];
  const float* fcw  = (const float*)d_in[9];
  const float* fcb  = (const float*)d_in[10];

  const int DYN_LDS = 72 * 1024;  // pad static 24KB -> 96KB: 1 block/CU

  auto inst = [&](int i, f16*& hb0, f16*& hb1, float*& part, int*& flags,
                  int*& ids, int*& dec) {
    f16* base = (f16*)d_ws + (size_t)i * INST_F16;
    hb0 = base;
    hb1 = base + (size_t)4 * H_SLOT;
    part = (float*)(base + (size_t)6 * H_SLOT);
    flags = (int*)(part + 16384);
    ids = flags + NFLAGS;
    dec = ids + 256;
  };

  int nabl = (ws_size >= 3 * INST_F16 * sizeof(f16)) ? 2 : 0;
  f16 *hb0, *hb1; float* part; int *flags, *ids, *dec;

  if (nabl) {
    hipFuncSetAttribute((const void*)gru_main<2, 256>,
                        hipFuncAttributeMaxDynamicSharedMemorySize, DYN_LDS);
    hipFuncSetAttribute((const void*)gru_main<1, 256>,
                        hipFuncAttributeMaxDynamicSharedMemorySize, DYN_LDS);
    // D1: NOSYNC ablation (races in its own buffers; timing = compute rate)
    inst(2, hb0, hb1, part, flags, ids, dec);
    init_ws<<<1024, 256, 0, stream>>>(hb0, flags);
    gru_main<2, 256><<<256, 512, DYN_LDS, stream>>>(
        x, Wih0, Whh0, Wih1, Whh1, bih0, bhh0, bih1, bhh1, fcw, hb0, hb1,
        part, flags, ids, dec);
    // D2: SOLO ablation (L0 recurrence + inter-slice sync only)
    inst(1, hb0, hb1, part, flags, ids, dec);
    init_ws<<<1024, 256, 0, stream>>>(hb0, flags);
    gru_main<1, 256><<<256, 512, DYN_LDS, stream>>>(
        x, Wih0, Whh0, Wih1, Whh1, bih0, bhh0, bih1, bhh1, fcw, hb0, hb1,
        part, flags, ids, dec);
  }
  // D3: real kernel (full protocol, produces output) — runs last
  hipFuncSetAttribute((const void*)gru_main<0, T_>,
                      hipFuncAttributeMaxDynamicSharedMemorySize, DYN_LDS);
  inst(0, hb0, hb1, part, flags, ids, dec);
  init_ws<<<1024, 256, 0, stream>>>(hb0, flags);
  gru_main<0, T_><<<256, 512, DYN_LDS, stream>>>(
      x, Wih0, Whh0, Wih1, Whh1, bih0, bhh0, bih1, bhh1, fcw, hb0, hb1, part,
      flags, ids, dec);
  fc_reduce<<<4, 256, 0, stream>>>(part, fcb, (float*)d_out);
}